// Round 3
// baseline (1254.199 us; speedup 1.0000x reference)
//
#include <hip/hip_runtime.h>
#include <stdint.h>
#include <math.h>

#define B_   16
#define T_   750
#define NC_  20
#define KNB_ 150   // T/5
#define KB_  37    // T/20

typedef _Float16 f16x8 __attribute__((ext_vector_type(8)));
typedef _Float16 f16x4 __attribute__((ext_vector_type(4)));
typedef float    f32x4 __attribute__((ext_vector_type(4)));
typedef float    f32x16 __attribute__((ext_vector_type(16)));

// ---- flat output layout (f32), concatenated in reference return order ----
static constexpr long long O_VS  = 0;                       // [16,20]
static constexpr long long O_EA  = 320;                     // [16,150,2048]
static constexpr long long O_EB  = 320 + 4915200LL;
static constexpr long long O_HA  = 320 + 2*4915200LL;
static constexpr long long O_HB  = O_HA + 1212416LL;
static constexpr long long O_IDX = O_HB + 1212416LL;        // [16,150]
static constexpr long long O_ACT = O_IDX + 2400LL;          // [16,750]
static constexpr long long O_CAS = O_ACT + 12000LL;         // [16,750,20]
static constexpr long long O_EMB = O_CAS + 240000LL;        // [16,750,2048]

// ---- workspace layout (fast path), bytes ----
static constexpr long long WX_ELE   = 16LL * 752 * 2048;          // f16 elements
static constexpr long long W_XHI    = 0;
static constexpr long long W_XLO    = W_XHI + WX_ELE * 2;
static constexpr long long WW_ELE   = 2LL * 16 * 32 * 12288;
static constexpr long long W_WHI    = W_XLO + WX_ELE * 2;
static constexpr long long W_WLO    = W_WHI + WW_ELE * 2;
static constexpr long long W_SEL    = W_WLO + WW_ELE * 2;
static constexpr long long W_VS     = W_SEL + 40960;
static constexpr long long W_NEED   = W_VS + 4096;

__device__ __forceinline__ void gload16(const void* g, void* l) {
    __builtin_amdgcn_global_load_lds(
        (const __attribute__((address_space(1))) unsigned int*)g,
        (__attribute__((address_space(3))) unsigned int*)l, 16, 0, 0);
}

// =====================================================================
// P1: split x -> x_hi/x_lo f16, padded rows (t=-1 and t=750) zeroed
// =====================================================================
__global__ __launch_bounds__(256) void xsplit(
    const float* __restrict__ x, _Float16* __restrict__ xh, _Float16* __restrict__ xl)
{
    long i = (long)blockIdx.x * 256 + threadIdx.x;
    int row = (int)(i >> 9);
    int c4  = (int)(i & 511);
    int b = row / 752, tr = row - b * 752;
    int t = tr - 1;
    float4 v = make_float4(0.f, 0.f, 0.f, 0.f);
    if (t >= 0 && t < T_)
        v = *reinterpret_cast<const float4*>(x + ((long)(b * T_ + t) * 2048 + c4 * 4));
    float vv[4] = {v.x, v.y, v.z, v.w};
    f16x4 h, l;
    #pragma unroll
    for (int j = 0; j < 4; ++j) {
        _Float16 hi = (_Float16)vv[j];
        h[j] = hi;
        l[j] = (_Float16)(vv[j] - (float)hi);
    }
    long o = (long)row * 2048 + c4 * 4;
    *reinterpret_cast<f16x4*>(xh + o) = h;
    *reinterpret_cast<f16x4*>(xl + o) = l;
}

// =====================================================================
// P2: split w*512 -> swizzled LDS-image layout
// image per (br,nt,chunk): [tap3][co128][q4][8 f16], q = g ^ ((co>>1)&3)
// =====================================================================
__global__ __launch_bounds__(64) void wsplit(
    const float* __restrict__ w_rgb, const float* __restrict__ w_flow,
    _Float16* __restrict__ wh, _Float16* __restrict__ wl)
{
    const int br   = blockIdx.x >> 11;
    const int co_g = blockIdx.x & 2047;
    const int tid  = threadIdx.x;
    const float* w = (br ? w_flow : w_rgb) + (long)co_g * 3072;   // [ci][k]
    __shared__ float wsrc[3072];
    for (int i = tid; i < 768; i += 64)
        reinterpret_cast<float4*>(wsrc)[i] = reinterpret_cast<const float4*>(w)[i];
    __syncthreads();
    const int nt = co_g >> 7, co = co_g & 127;
    for (int p = tid; p < 384; p += 64) {           // 128 octets x 3 taps
        int oct = p / 3, k = p - oct * 3;
        int chunk = oct >> 2, g = oct & 3;
        int q = g ^ ((co >> 1) & 3);
        f16x8 h, l;
        #pragma unroll
        for (int j = 0; j < 8; ++j) {
            float v = wsrc[(oct * 8 + j) * 3 + k] * 512.f;
            _Float16 hi = (_Float16)v;
            h[j] = hi;
            l[j] = (_Float16)(v - (float)hi);
        }
        long o = ((long)(br * 16 + nt) * 32 + chunk) * 12288 + k * 4096 + co * 32 + q * 8;
        *reinterpret_cast<f16x8*>(wh + o) = h;
        *reinterpret_cast<f16x8*>(wl + o) = l;
    }
}

// =====================================================================
// K1: conv1d(K=3,pad=1) via split-f16 MFMA 32x32x16. Tile 192t x 128co,
// 4 waves (each 96x64 = 3x2 of 32x32 frags). ADD=0: rgb, ADD=1: flow +=.
// XCD-grouped swizzle: each XCD owns 2 nt columns (W slice L2-resident).
// =====================================================================
template<int ADD>
__global__ __launch_bounds__(256, 2) void conv_mfma(
    const _Float16* __restrict__ xh, const _Float16* __restrict__ xl,
    const _Float16* __restrict__ wh, const _Float16* __restrict__ wl,
    const float* __restrict__ bias, float* __restrict__ emb)
{
    __shared__ _Float16 XhL[6272], XlL[6272];      // 196 rows x 32 f16 (swizzled)
    __shared__ _Float16 WhL[12288], WlL[12288];    // [tap3][co128][32 f16] (swizzled)

    const int tid  = threadIdx.x;
    const int lane = tid & 63;
    const int wid  = tid >> 6;
    const int wm = wid >> 1, wn = wid & 1;
    const int l31 = lane & 31, lg2 = lane >> 5;

    // bijective XCD-grouping: 1024 blocks = 8 xcd * 128; nt = lid>>6
    const int bid = blockIdx.y * 16 + blockIdx.x;
    const int lid = (bid & 7) * 128 + (bid >> 3);
    const int nt  = lid >> 6;                  // 0..15 (2 per XCD)
    const int bty = lid & 63;
    const int b   = bty >> 2;
    const int tt  = bty & 3;
    const int t0  = tt * 192;

    f32x16 acc[3][2];
    #pragma unroll
    for (int m = 0; m < 3; ++m)
        #pragma unroll
        for (int n = 0; n < 2; ++n)
            #pragma unroll
            for (int e = 0; e < 16; ++e) acc[m][n][e] = 0.f;

    const long xrowbase = (long)b * 752 + t0;
    for (int chunk = 0; chunk < 32; ++chunk) {
        // ---- stage X (both halves): 776 slots of 16B, swizzled source ----
        const int cibase = ADD * 1024 + chunk * 32;
        for (int s = tid; s < 776; s += 256) {
            int r = s >> 2, q = s & 3;
            int g = q ^ ((r >> 1) & 3);
            long goff = (xrowbase + r) * 2048 + cibase + g * 8;
            int lbase = (s & ~63) * 8;
            gload16(xh + goff, XhL + lbase);
            gload16(xl + goff, XlL + lbase);
        }
        // ---- stage W (both halves): 1536 slots of 16B, linear (pre-swizzled) ----
        const long wbase = ((long)(ADD * 16 + nt) * 32 + chunk) * 12288;
        for (int s = tid; s < 1536; s += 256) {
            int lbase = (s & ~63) * 8;
            gload16(wh + wbase + (long)s * 8, WhL + lbase);
            gload16(wl + wbase + (long)s * 8, WlL + lbase);
        }
        __syncthreads();

        #pragma unroll
        for (int k = 0; k < 3; ++k) {
            #pragma unroll
            for (int s2 = 0; s2 < 2; ++s2) {       // K-step within 32-ci chunk
                const int g = 2 * s2 + lg2;
                f16x8 ah[3], al[3], bh[2], bl[2];
                #pragma unroll
                for (int m = 0; m < 3; ++m) {
                    int r = wm * 96 + m * 32 + l31 + k;
                    int off = r * 32 + ((g ^ ((r >> 1) & 3)) * 8);
                    ah[m] = *reinterpret_cast<const f16x8*>(&XhL[off]);
                    al[m] = *reinterpret_cast<const f16x8*>(&XlL[off]);
                }
                #pragma unroll
                for (int n = 0; n < 2; ++n) {
                    int co = wn * 64 + n * 32 + l31;
                    int off = k * 4096 + co * 32 + ((g ^ ((co >> 1) & 3)) * 8);
                    bh[n] = *reinterpret_cast<const f16x8*>(&WhL[off]);
                    bl[n] = *reinterpret_cast<const f16x8*>(&WlL[off]);
                }
                #pragma unroll
                for (int m = 0; m < 3; ++m)
                    #pragma unroll
                    for (int n = 0; n < 2; ++n) {
                        acc[m][n] = __builtin_amdgcn_mfma_f32_32x32x16_f16(ah[m], bh[n], acc[m][n], 0, 0, 0);
                        acc[m][n] = __builtin_amdgcn_mfma_f32_32x32x16_f16(al[m], bh[n], acc[m][n], 0, 0, 0);
                        acc[m][n] = __builtin_amdgcn_mfma_f32_32x32x16_f16(ah[m], bl[n], acc[m][n], 0, 0, 0);
                    }
            }
        }
        __syncthreads();
    }

    // ---- epilogue: relu(acc/512 + bias); ADD pass accumulates ----
    const float sc = 1.f / 512.f;
    #pragma unroll
    for (int n = 0; n < 2; ++n) {
        const int co = nt * 128 + wn * 64 + n * 32 + l31;
        const float bs = bias[co];
        #pragma unroll
        for (int m = 0; m < 3; ++m) {
            #pragma unroll
            for (int reg = 0; reg < 16; ++reg) {
                int row32 = (reg & 3) + 8 * (reg >> 2) + 4 * lg2;
                int t = t0 + wm * 96 + m * 32 + row32;
                if (t < T_) {
                    long o = ((long)b * T_ + t) * 2048 + co;
                    float v = fmaxf(fmaf(acc[m][n][reg], sc, bs), 0.f);
                    if (ADD) emb[o] += v;
                    else     emb[o]  = v;
                }
            }
        }
    }
}

// =====================================================================
// K2: cas + actionness. Thread-per-(t,c): no cross-lane reduction.
// 750 blocks x 320 threads; 16 flat rows per block (batch-crossing OK).
// =====================================================================
__global__ __launch_bounds__(320) void cas_tc(
    const float* __restrict__ emb, const float* __restrict__ wcls,
    float* __restrict__ cas, float* __restrict__ act)
{
    const int t0g = blockIdx.x * 16;          // flat row base (b*T + t)
    const int tid = threadIdx.x;
    const int tl  = tid / 20, c = tid % 20;   // 16 x 20 = 320
    __shared__ float embS[16][132];
    __shared__ float wS[20][132];
    __shared__ float casS[16][20];

    float acc = 0.f;
    for (int cc = 0; cc < 2048; cc += 128) {
        for (int s = tid; s < 512; s += 320) {
            int r = s >> 5, q = s & 31;
            *reinterpret_cast<float4*>(&embS[r][q * 4]) =
                *reinterpret_cast<const float4*>(&emb[((long)t0g + r) * 2048 + cc + q * 4]);
        }
        for (int s = tid; s < 640; s += 320) {
            int r = s >> 5, q = s & 31;
            *reinterpret_cast<float4*>(&wS[r][q * 4]) =
                *reinterpret_cast<const float4*>(&wcls[(long)r * 2048 + cc + q * 4]);
        }
        __syncthreads();
        #pragma unroll
        for (int q = 0; q < 32; ++q) {
            float4 a = *reinterpret_cast<const float4*>(&embS[tl][q * 4]);
            float4 w = *reinterpret_cast<const float4*>(&wS[c][q * 4]);
            acc = fmaf(a.x, w.x, acc); acc = fmaf(a.y, w.y, acc);
            acc = fmaf(a.z, w.z, acc); acc = fmaf(a.w, w.w, acc);
        }
        __syncthreads();
    }
    float r = acc > 0.f ? acc : 0.f;
    cas[(long)(t0g + tl) * NC_ + c] = r;
    casS[tl][c] = r;
    __syncthreads();
    if (tid < 16) {
        float s = 0.f;
        #pragma unroll
        for (int c2 = 0; c2 < NC_; ++c2) s += casS[tid][c2];
        act[t0g + tid] = s;
    }
}

// ===================== fallback f32 conv (round-1, known-good) =====================
__global__ __launch_bounds__(256) void conv_embed_f32(
    const float* __restrict__ x,
    const float* __restrict__ w_rgb, const float* __restrict__ b_rgb,
    const float* __restrict__ w_flow, const float* __restrict__ b_flow,
    float* __restrict__ emb)
{
    __shared__ float Xs[2][16][132];
    __shared__ float Ws[2][16][3][68];
    const int tid = threadIdx.x;
    const int tx  = tid & 15;
    const int ty  = tid >> 4;
    const int co0 = blockIdx.x * 64;
    const int tb  = blockIdx.y;
    const int t0  = (tb % 6) * 128;
    const int b   = tb / 6;
    const float* xb = x + (long long)b * T_ * 2048;
    float acc[2][8][4];
    #pragma unroll
    for (int br = 0; br < 2; ++br)
        #pragma unroll
        for (int i = 0; i < 8; ++i)
            #pragma unroll
            for (int j = 0; j < 4; ++j) acc[br][i][j] = 0.f;
    for (int cc = 0; cc < 1024; cc += 16) {
        for (int it = tid; it < 1040; it += 256) {
            int br = (it >= 520);
            int r4 = it - br * 520;
            int r  = r4 >> 2;
            int cq = r4 & 3;
            int t  = t0 - 1 + r;
            float4 v = make_float4(0.f, 0.f, 0.f, 0.f);
            if (t >= 0 && t < T_)
                v = *reinterpret_cast<const float4*>(xb + (long long)t * 2048 + br * 1024 + cc + cq * 4);
            Xs[br][cq * 4 + 0][r] = v.x;
            Xs[br][cq * 4 + 1][r] = v.y;
            Xs[br][cq * 4 + 2][r] = v.z;
            Xs[br][cq * 4 + 3][r] = v.w;
        }
        for (int it = tid; it < 1536; it += 256) {
            int br = (it >= 768);
            int r  = it - br * 768;
            int co = r / 12;
            int fq = r - co * 12;
            const float* wsrc = (br ? w_flow : w_rgb) + ((long long)(co0 + co) * 1024 + cc) * 3 + fq * 4;
            float4 v = *reinterpret_cast<const float4*>(wsrc);
            float vv[4] = {v.x, v.y, v.z, v.w};
            #pragma unroll
            for (int j = 0; j < 4; ++j) {
                int f  = fq * 4 + j;
                int ci = f / 3;
                int kk = f - ci * 3;
                Ws[br][ci][kk][co] = vv[j];
            }
        }
        __syncthreads();
        #pragma unroll
        for (int ci = 0; ci < 16; ++ci) {
            float xr[2][12];
            #pragma unroll
            for (int br = 0; br < 2; ++br) {
                const float4* xp = reinterpret_cast<const float4*>(&Xs[br][ci][ty * 8]);
                float4 a0 = xp[0], a1 = xp[1], a2 = xp[2];
                xr[br][0] = a0.x; xr[br][1] = a0.y; xr[br][2]  = a0.z; xr[br][3]  = a0.w;
                xr[br][4] = a1.x; xr[br][5] = a1.y; xr[br][6]  = a1.z; xr[br][7]  = a1.w;
                xr[br][8] = a2.x; xr[br][9] = a2.y; xr[br][10] = a2.z; xr[br][11] = a2.w;
            }
            #pragma unroll
            for (int br = 0; br < 2; ++br) {
                #pragma unroll
                for (int k = 0; k < 3; ++k) {
                    const float4 bv = *reinterpret_cast<const float4*>(&Ws[br][ci][k][tx * 4]);
                    float bw[4] = {bv.x, bv.y, bv.z, bv.w};
                    #pragma unroll
                    for (int i = 0; i < 8; ++i)
                        #pragma unroll
                        for (int j = 0; j < 4; ++j)
                            acc[br][i][j] = fmaf(xr[br][i + k], bw[j], acc[br][i][j]);
                }
            }
        }
        __syncthreads();
    }
    const float4 brv = *reinterpret_cast<const float4*>(b_rgb + co0 + tx * 4);
    const float4 bfv = *reinterpret_cast<const float4*>(b_flow + co0 + tx * 4);
    float brr[4] = {brv.x, brv.y, brv.z, brv.w};
    float bff[4] = {bfv.x, bfv.y, bfv.z, bfv.w};
    #pragma unroll
    for (int i = 0; i < 8; ++i) {
        int t = t0 + ty * 8 + i;
        if (t < T_) {
            float ov[4];
            #pragma unroll
            for (int j = 0; j < 4; ++j) {
                float r = acc[0][i][j] + brr[j];
                float f = acc[1][i][j] + bff[j];
                r = r > 0.f ? r : 0.f;
                f = f > 0.f ? f : 0.f;
                ov[j] = r + f;
            }
            float4 o; o.x = ov[0]; o.y = ov[1]; o.z = ov[2]; o.w = ov[3];
            *reinterpret_cast<float4*>(emb + ((long long)b * T_ + t) * 2048 + co0 + tx * 4) = o;
        }
    }
}

// ===================== exact top-k machinery =====================
__device__ inline float keyval(unsigned long long k) {
    return __uint_as_float(~(unsigned)(k >> 32));
}

__device__ inline void bitonic_sort_u64(unsigned long long* keys, int tid)
{
    for (unsigned size = 2; size <= 1024; size <<= 1) {
        for (unsigned stride = size >> 1; stride > 0; stride >>= 1) {
            __syncthreads();
            for (int j = tid; j < 512; j += 256) {
                unsigned i = ((j & ~(stride - 1)) << 1) | (j & (stride - 1));
                unsigned p = i + stride;
                bool asc = ((i & size) == 0);
                unsigned long long a = keys[i];
                unsigned long long c = keys[p];
                bool sw = asc ? (a > c) : (a < c);
                if (sw) { keys[i] = c; keys[p] = a; }
            }
        }
    }
    __syncthreads();
}

__device__ inline void bitonic_sort_u32(unsigned* keys, int tid)
{
    for (unsigned size = 2; size <= 1024; size <<= 1) {
        for (unsigned stride = size >> 1; stride > 0; stride >>= 1) {
            __syncthreads();
            for (int j = tid; j < 512; j += 256) {
                unsigned i = ((j & ~(stride - 1)) << 1) | (j & (stride - 1));
                unsigned p = i + stride;
                bool asc = ((i & size) == 0);
                unsigned a = keys[i];
                unsigned c = keys[p];
                bool sw = asc ? (a > c) : (a < c);
                if (sw) { keys[i] = c; keys[p] = a; }
            }
        }
    }
    __syncthreads();
}

// ===================== K3: per-batch mining =====================
__global__ __launch_bounds__(256) void analysis_kernel(
    const float* __restrict__ act, float* __restrict__ idx_out, int* __restrict__ sel)
{
    const int b   = blockIdx.x;
    const int tid = threadIdx.x;
    __shared__ float av[T_];
    __shared__ unsigned long long keys[1024];
    __shared__ unsigned char bin[T_];
    __shared__ float medmax[2];

    for (int t = tid; t < T_; t += 256) av[t] = act[b * T_ + t];
    __syncthreads();

    for (int p = tid; p < 1024; p += 256) {
        unsigned long long k = ~0ull;
        if (p < T_) k = ((unsigned long long)(~__float_as_uint(av[p])) << 32) | (unsigned)p;
        keys[p] = k;
    }
    bitonic_sort_u64(keys, tid);
    if (tid < KNB_) {
        int t = (int)(keys[tid] & 0xffffffffu);
        idx_out[b * KNB_ + tid] = (float)t;
        sel[(b * 4 + 0) * 160 + tid] = t;
    }
    if (tid == 0) {
        medmax[0] = 0.5f * (keyval(keys[374]) + keyval(keys[375]));
        medmax[1] = keyval(keys[0]);
    }
    __syncthreads();
    const float med = medmax[0];
    const float mx  = medmax[1];
    for (int t = tid; t < T_; t += 256) bin[t] = (av[t] > med) ? 1 : 0;
    __syncthreads();

    for (int p = tid; p < 1024; p += 256) {
        unsigned long long k = ~0ull;
        if (p < T_) k = ((unsigned long long)(~__float_as_uint(mx - av[p])) << 32) | (unsigned)p;
        keys[p] = k;
    }
    bitonic_sort_u64(keys, tid);
    if (tid < KNB_) sel[(b * 4 + 1) * 160 + tid] = (int)(keys[tid] & 0xffffffffu);
    __syncthreads();

    for (int p = tid; p < 1024; p += 256) {
        unsigned long long k = ~0ull;
        if (p < T_) {
            int b0 = (p >= 1) ? bin[p - 1] : 0;
            int b1 = bin[p];
            int b2 = (p + 1 < T_) ? bin[p + 1] : 0;
            int e3 = b0 & b1 & b2;
            int e6 = 1;
            #pragma unroll
            for (int d = -3; d <= 2; ++d) {
                int q = p + d;
                e6 &= (q >= 0 && q < T_) ? (int)bin[q] : 0;
            }
            float s = (e3 && !e6) ? av[p] : 0.f;
            k = ((unsigned long long)(~__float_as_uint(s)) << 32) | (unsigned)p;
        }
        keys[p] = k;
    }
    bitonic_sort_u64(keys, tid);
    if (tid < KB_) sel[(b * 4 + 2) * 160 + tid] = (int)(keys[tid] & 0xffffffffu);
    __syncthreads();

    for (int p = tid; p < 1024; p += 256) {
        unsigned long long k = ~0ull;
        if (p < T_) {
            int b0 = (p >= 1) ? bin[p - 1] : 0;
            int b1 = bin[p];
            int b2 = (p + 1 < T_) ? bin[p + 1] : 0;
            int d3 = b0 | b1 | b2;
            int d6 = 0;
            #pragma unroll
            for (int d = -2; d <= 3; ++d) {
                int q = p + d;
                d6 |= (q >= 0 && q < T_) ? (int)bin[q] : 0;
            }
            float s = (d6 && !d3) ? av[p] : 0.f;
            k = ((unsigned long long)(~__float_as_uint(s)) << 32) | (unsigned)p;
        }
        keys[p] = k;
    }
    bitonic_sort_u64(keys, tid);
    if (tid < KB_) sel[(b * 4 + 3) * 160 + tid] = (int)(keys[tid] & 0xffffffffu);
}

// ===================== K4: per-(b,c) top-150 mean =====================
__global__ __launch_bounds__(256) void video_topk(
    const float* __restrict__ cas, float* __restrict__ vs)
{
    const int bc  = blockIdx.x;
    const int b   = bc / NC_;
    const int c   = bc - b * NC_;
    const int tid = threadIdx.x;
    __shared__ unsigned keys[1024];
    __shared__ float red[4];
    for (int p = tid; p < 1024; p += 256)
        keys[p] = (p < T_) ? ~__float_as_uint(cas[((long long)b * T_ + p) * NC_ + c]) : 0xffffffffu;
    bitonic_sort_u32(keys, tid);
    float v = (tid < KNB_) ? __uint_as_float(~keys[tid]) : 0.f;
    #pragma unroll
    for (int off = 32; off > 0; off >>= 1) v += __shfl_down(v, off, 64);
    const int lane = tid & 63, wid = tid >> 6;
    if (lane == 0) red[wid] = v;
    __syncthreads();
    if (tid == 0) vs[bc] = (red[0] + red[1] + red[2] + red[3]) / 150.f;
}

__global__ void softmax20(const float* __restrict__ vs, float* __restrict__ out)
{
    const int b   = blockIdx.x;
    const int tid = threadIdx.x;
    float v = (tid < NC_) ? vs[b * NC_ + tid] : -INFINITY;
    float m = v;
    #pragma unroll
    for (int off = 32; off > 0; off >>= 1) m = fmaxf(m, __shfl_xor(m, off, 64));
    float e = (tid < NC_) ? expf(v - m) : 0.f;
    float s = e;
    #pragma unroll
    for (int off = 32; off > 0; off >>= 1) s += __shfl_xor(s, off, 64);
    if (tid < NC_) out[b * NC_ + tid] = e / s;
}

// ===================== K6: gather selected rows =====================
__global__ __launch_bounds__(256) void gather_rows(
    const float* __restrict__ emb, const int* __restrict__ sel, float* __restrict__ out)
{
    const int r = blockIdx.x;
    const int b = r / 374;
    const int q = r - b * 374;
    int g, p; long long dst;
    if (q < 150)      { g = 0; p = q;       dst = O_EA + (long long)(b * KNB_ + p) * 2048; }
    else if (q < 300) { g = 1; p = q - 150; dst = O_EB + (long long)(b * KNB_ + p) * 2048; }
    else if (q < 337) { g = 2; p = q - 300; dst = O_HA + (long long)(b * KB_ + p) * 2048; }
    else              { g = 3; p = q - 337; dst = O_HB + (long long)(b * KB_ + p) * 2048; }
    const int t = sel[(b * 4 + g) * 160 + p];
    const float4* src = reinterpret_cast<const float4*>(emb + ((long long)b * T_ + t) * 2048);
    float4* d = reinterpret_cast<float4*>(out + dst);
    for (int i = threadIdx.x; i < 512; i += 256) d[i] = src[i];
}

extern "C" void kernel_launch(void* const* d_in, const int* in_sizes, int n_in,
                              void* d_out, int out_size, void* d_ws, size_t ws_size,
                              hipStream_t stream)
{
    const float* x      = (const float*)d_in[0];
    const float* w_rgb  = (const float*)d_in[1];
    const float* b_rgb  = (const float*)d_in[2];
    const float* w_flow = (const float*)d_in[3];
    const float* b_flow = (const float*)d_in[4];
    const float* w_cls  = (const float*)d_in[5];

    float* out  = (float*)d_out;
    float* emb  = out + O_EMB;
    float* cas  = out + O_CAS;
    float* act  = out + O_ACT;
    float* idxo = out + O_IDX;

    const bool fast = (ws_size >= (size_t)W_NEED);

    int*   sel;
    float* vs;
    if (fast) {
        sel = (int*)((char*)d_ws + W_SEL);
        vs  = (float*)((char*)d_ws + W_VS);
        _Float16* xh = (_Float16*)((char*)d_ws + W_XHI);
        _Float16* xl = (_Float16*)((char*)d_ws + W_XLO);
        _Float16* wh = (_Float16*)((char*)d_ws + W_WHI);
        _Float16* wl = (_Float16*)((char*)d_ws + W_WLO);

        xsplit<<<24064, 256, 0, stream>>>(x, xh, xl);
        wsplit<<<4096, 64, 0, stream>>>(w_rgb, w_flow, wh, wl);
        conv_mfma<0><<<dim3(16, 64), 256, 0, stream>>>(xh, xl, wh, wl, b_rgb, emb);
        conv_mfma<1><<<dim3(16, 64), 256, 0, stream>>>(xh, xl, wh, wl, b_flow, emb);
    } else {
        sel = (int*)d_ws;
        vs  = (float*)((char*)d_ws + 64 * 1024);
        conv_embed_f32<<<dim3(32, 96), 256, 0, stream>>>(x, w_rgb, b_rgb, w_flow, b_flow, emb);
    }

    cas_tc<<<750, 320, 0, stream>>>(emb, w_cls, cas, act);
    analysis_kernel<<<B_, 256, 0, stream>>>(act, idxo, sel);
    video_topk<<<B_ * NC_, 256, 0, stream>>>(cas, vs);
    softmax20<<<B_, 64, 0, stream>>>(vs, out + O_VS);
    gather_rows<<<B_ * 374, 256, 0, stream>>>(emb, sel, out);
}

// Round 4
// 1136.682 us; speedup vs baseline: 1.1034x; 1.1034x over previous
//
#include <hip/hip_runtime.h>
#include <stdint.h>
#include <math.h>

#define B_   16
#define T_   750
#define NC_  20
#define KNB_ 150   // T/5
#define KB_  37    // T/20

typedef _Float16 f16x8 __attribute__((ext_vector_type(8)));
typedef _Float16 f16x4 __attribute__((ext_vector_type(4)));
typedef float    f32x4 __attribute__((ext_vector_type(4)));

// ---- flat output layout (f32), concatenated in reference return order ----
static constexpr long long O_VS  = 0;                       // [16,20]
static constexpr long long O_EA  = 320;                     // [16,150,2048]
static constexpr long long O_EB  = 320 + 4915200LL;
static constexpr long long O_HA  = 320 + 2*4915200LL;
static constexpr long long O_HB  = O_HA + 1212416LL;
static constexpr long long O_IDX = O_HB + 1212416LL;        // [16,150]
static constexpr long long O_ACT = O_IDX + 2400LL;          // [16,750]
static constexpr long long O_CAS = O_ACT + 12000LL;         // [16,750,20]
static constexpr long long O_EMB = O_CAS + 240000LL;        // [16,750,2048]

// ---- workspace layout (fast path), bytes ----
static constexpr long long WX_ELE   = 16LL * 752 * 2048;          // f16 elements
static constexpr long long W_XHI    = 0;
static constexpr long long W_XLO    = W_XHI + WX_ELE * 2;
static constexpr long long WW_ELE   = 2LL * 16 * 32 * 12288;
static constexpr long long W_WHI    = W_XLO + WX_ELE * 2;
static constexpr long long W_WLO    = W_WHI + WW_ELE * 2;
static constexpr long long W_SEL    = W_WLO + WW_ELE * 2;         // 16*4*160 ints
static constexpr long long W_VS     = W_SEL + 40960;
static constexpr long long W_MED    = W_VS + 4096;                // 16*2 floats
static constexpr long long W_NEED   = W_MED + 256;

__device__ __forceinline__ void gload16(const void* g, void* l) {
    __builtin_amdgcn_global_load_lds(
        (const __attribute__((address_space(1))) unsigned int*)g,
        (__attribute__((address_space(3))) unsigned int*)l, 16, 0, 0);
}

// =====================================================================
// P1: split x -> x_hi/x_lo f16, padded rows (t=-1 and t=750) zeroed
// =====================================================================
__global__ __launch_bounds__(256) void xsplit(
    const float* __restrict__ x, _Float16* __restrict__ xh, _Float16* __restrict__ xl)
{
    long i = (long)blockIdx.x * 256 + threadIdx.x;
    int row = (int)(i >> 9);
    int c4  = (int)(i & 511);
    int b = row / 752, tr = row - b * 752;
    int t = tr - 1;
    float4 v = make_float4(0.f, 0.f, 0.f, 0.f);
    if (t >= 0 && t < T_)
        v = *reinterpret_cast<const float4*>(x + ((long)(b * T_ + t) * 2048 + c4 * 4));
    float vv[4] = {v.x, v.y, v.z, v.w};
    f16x4 h, l;
    #pragma unroll
    for (int j = 0; j < 4; ++j) {
        _Float16 hi = (_Float16)vv[j];
        h[j] = hi;
        l[j] = (_Float16)(vv[j] - (float)hi);
    }
    long o = (long)row * 2048 + c4 * 4;
    *reinterpret_cast<f16x4*>(xh + o) = h;
    *reinterpret_cast<f16x4*>(xl + o) = l;
}

// =====================================================================
// P2: split w*512 -> frag-contiguous image [br][nt][chunk][k][co128][g4][8]
// (no XOR: consumed by direct global->register frag loads, lane-coalesced)
// =====================================================================
__global__ __launch_bounds__(64) void wsplit(
    const float* __restrict__ w_rgb, const float* __restrict__ w_flow,
    _Float16* __restrict__ wh, _Float16* __restrict__ wl)
{
    const int br   = blockIdx.x >> 11;
    const int co_g = blockIdx.x & 2047;
    const int tid  = threadIdx.x;
    const float* w = (br ? w_flow : w_rgb) + (long)co_g * 3072;   // [ci][k]
    __shared__ float wsrc[3072];
    for (int i = tid; i < 768; i += 64)
        reinterpret_cast<float4*>(wsrc)[i] = reinterpret_cast<const float4*>(w)[i];
    __syncthreads();
    const int nt = co_g >> 7, co = co_g & 127;
    for (int p = tid; p < 384; p += 64) {           // 128 octets x 3 taps
        int oct = p / 3, k = p - oct * 3;
        int chunk = oct >> 2, g = oct & 3;
        f16x8 h, l;
        #pragma unroll
        for (int j = 0; j < 8; ++j) {
            float v = wsrc[(oct * 8 + j) * 3 + k] * 512.f;
            _Float16 hi = (_Float16)v;
            h[j] = hi;
            l[j] = (_Float16)(v - (float)hi);
        }
        long o = ((long)(br * 16 + nt) * 32 + chunk) * 12288 + k * 4096 + co * 32 + g * 8;
        *reinterpret_cast<f16x8*>(wh + o) = h;
        *reinterpret_cast<f16x8*>(wl + o) = l;
    }
}

// =====================================================================
// K1: conv1d(K=3,pad=1), split-f16 MFMA 16x16x32. Tile 192t x 128co,
// 4 waves (each 96t x 64co = 6x4 frags). X staged in LDS (swizzled,
// conflict-free, verified R2); W loaded global->reg (frag-contiguous,
// L2-resident), pipelined one k-tap ahead. ADD=0: rgb, ADD=1: flow +=.
// =====================================================================
template<int ADD>
__global__ __launch_bounds__(256, 2) void conv_mfma(
    const _Float16* __restrict__ xh, const _Float16* __restrict__ xl,
    const _Float16* __restrict__ wh, const _Float16* __restrict__ wl,
    const float* __restrict__ bias, float* __restrict__ emb)
{
    __shared__ _Float16 XhL[6272], XlL[6272];      // 196 rows x 32 f16 (swizzled)

    const int tid  = threadIdx.x;
    const int lane = tid & 63;
    const int wid  = tid >> 6;
    const int wm = wid >> 1, wn = wid & 1;
    const int lrow = lane & 15, lg = lane >> 4;
    const int nt = blockIdx.x;                 // natural order: 16 nt share X tile
    const int b  = blockIdx.y >> 2;
    const int tt = blockIdx.y & 3;
    const int t0 = tt * 192;

    f32x4 acc[6][4];
    #pragma unroll
    for (int m = 0; m < 6; ++m)
        #pragma unroll
        for (int n = 0; n < 4; ++n)
            acc[m][n] = (f32x4){0.f, 0.f, 0.f, 0.f};

    const long xrowbase = (long)b * 752 + t0;
    const int  cibase0  = ADD * 1024;
    const long wslice   = ((long)(ADD * 16 + nt) * 32) * 12288;
    const int  wlane    = (wn * 64 + lrow) * 32 + lg * 8;

    for (int chunk = 0; chunk < 32; ++chunk) {
        const long wb = wslice + (long)chunk * 12288 + wlane;
        f16x8 bh0[4], bl0[4], bh1[4], bl1[4];
        // W frags for k=0 (issued before staging; land under the barrier)
        #pragma unroll
        for (int n = 0; n < 4; ++n) {
            bh0[n] = *reinterpret_cast<const f16x8*>(wh + wb + n * 512);
            bl0[n] = *reinterpret_cast<const f16x8*>(wl + wb + n * 512);
        }
        // ---- stage X (both halves): 776 slots of 16B, swizzled source ----
        const int cibase = cibase0 + chunk * 32;
        for (int s = tid; s < 776; s += 256) {
            int r = s >> 2, q = s & 3;
            int g = q ^ ((r >> 1) & 3);
            long goff = (xrowbase + r) * 2048 + cibase + g * 8;
            int lbase = (s & ~63) * 8;
            gload16(xh + goff, XhL + lbase);
            gload16(xl + goff, XlL + lbase);
        }
        __syncthreads();

        // ================= k = 0 (prefetch k=1 W frags) =================
        #pragma unroll
        for (int n = 0; n < 4; ++n) {
            bh1[n] = *reinterpret_cast<const f16x8*>(wh + wb + 4096 + n * 512);
            bl1[n] = *reinterpret_cast<const f16x8*>(wl + wb + 4096 + n * 512);
        }
        #pragma unroll
        for (int m = 0; m < 6; ++m) {
            int r = wm * 96 + m * 16 + lrow;
            int off = r * 32 + ((lg ^ ((r >> 1) & 3)) * 8);
            f16x8 ah = *reinterpret_cast<const f16x8*>(&XhL[off]);
            f16x8 al = *reinterpret_cast<const f16x8*>(&XlL[off]);
            #pragma unroll
            for (int n = 0; n < 4; ++n) {
                acc[m][n] = __builtin_amdgcn_mfma_f32_16x16x32_f16(ah, bh0[n], acc[m][n], 0, 0, 0);
                acc[m][n] = __builtin_amdgcn_mfma_f32_16x16x32_f16(al, bh0[n], acc[m][n], 0, 0, 0);
                acc[m][n] = __builtin_amdgcn_mfma_f32_16x16x32_f16(ah, bl0[n], acc[m][n], 0, 0, 0);
            }
        }
        // ================= k = 1 (prefetch k=2 into buf0) ===============
        #pragma unroll
        for (int n = 0; n < 4; ++n) {
            bh0[n] = *reinterpret_cast<const f16x8*>(wh + wb + 8192 + n * 512);
            bl0[n] = *reinterpret_cast<const f16x8*>(wl + wb + 8192 + n * 512);
        }
        #pragma unroll
        for (int m = 0; m < 6; ++m) {
            int r = wm * 96 + m * 16 + lrow + 1;
            int off = r * 32 + ((lg ^ ((r >> 1) & 3)) * 8);
            f16x8 ah = *reinterpret_cast<const f16x8*>(&XhL[off]);
            f16x8 al = *reinterpret_cast<const f16x8*>(&XlL[off]);
            #pragma unroll
            for (int n = 0; n < 4; ++n) {
                acc[m][n] = __builtin_amdgcn_mfma_f32_16x16x32_f16(ah, bh1[n], acc[m][n], 0, 0, 0);
                acc[m][n] = __builtin_amdgcn_mfma_f32_16x16x32_f16(al, bh1[n], acc[m][n], 0, 0, 0);
                acc[m][n] = __builtin_amdgcn_mfma_f32_16x16x32_f16(ah, bl1[n], acc[m][n], 0, 0, 0);
            }
        }
        // ================= k = 2 ========================================
        #pragma unroll
        for (int m = 0; m < 6; ++m) {
            int r = wm * 96 + m * 16 + lrow + 2;
            int off = r * 32 + ((lg ^ ((r >> 1) & 3)) * 8);
            f16x8 ah = *reinterpret_cast<const f16x8*>(&XhL[off]);
            f16x8 al = *reinterpret_cast<const f16x8*>(&XlL[off]);
            #pragma unroll
            for (int n = 0; n < 4; ++n) {
                acc[m][n] = __builtin_amdgcn_mfma_f32_16x16x32_f16(ah, bh0[n], acc[m][n], 0, 0, 0);
                acc[m][n] = __builtin_amdgcn_mfma_f32_16x16x32_f16(al, bh0[n], acc[m][n], 0, 0, 0);
                acc[m][n] = __builtin_amdgcn_mfma_f32_16x16x32_f16(ah, bl0[n], acc[m][n], 0, 0, 0);
            }
        }
        __syncthreads();
    }

    // ---- epilogue: relu(acc/512 + bias); ADD pass accumulates (R2-verified) ----
    const float sc = 1.f / 512.f;
    #pragma unroll
    for (int n = 0; n < 4; ++n) {
        const int co = nt * 128 + wn * 64 + n * 16 + lrow;
        const float bs = bias[co];
        #pragma unroll
        for (int m = 0; m < 6; ++m) {
            #pragma unroll
            for (int rg = 0; rg < 4; ++rg) {
                int t = t0 + wm * 96 + m * 16 + lg * 4 + rg;
                if (t < T_) {
                    long o = ((long)b * T_ + t) * 2048 + co;
                    float v = fmaxf(fmaf(acc[m][n][rg], sc, bs), 0.f);
                    if (ADD) emb[o] += v;
                    else     emb[o]  = v;
                }
            }
        }
    }
}

// =====================================================================
// K2: cas + actionness. Thread-per-(t,c): no cross-lane reduction.
// =====================================================================
__global__ __launch_bounds__(320) void cas_tc(
    const float* __restrict__ emb, const float* __restrict__ wcls,
    float* __restrict__ cas, float* __restrict__ act)
{
    const int t0g = blockIdx.x * 16;          // flat row base (b*T + t)
    const int tid = threadIdx.x;
    const int tl  = tid / 20, c = tid % 20;   // 16 x 20 = 320
    __shared__ float embS[16][132];
    __shared__ float wS[20][132];
    __shared__ float casS[16][20];

    float acc = 0.f;
    for (int cc = 0; cc < 2048; cc += 128) {
        for (int s = tid; s < 512; s += 320) {
            int r = s >> 5, q = s & 31;
            *reinterpret_cast<float4*>(&embS[r][q * 4]) =
                *reinterpret_cast<const float4*>(&emb[((long)t0g + r) * 2048 + cc + q * 4]);
        }
        for (int s = tid; s < 640; s += 320) {
            int r = s >> 5, q = s & 31;
            *reinterpret_cast<float4*>(&wS[r][q * 4]) =
                *reinterpret_cast<const float4*>(&wcls[(long)r * 2048 + cc + q * 4]);
        }
        __syncthreads();
        #pragma unroll
        for (int q = 0; q < 32; ++q) {
            float4 a = *reinterpret_cast<const float4*>(&embS[tl][q * 4]);
            float4 w = *reinterpret_cast<const float4*>(&wS[c][q * 4]);
            acc = fmaf(a.x, w.x, acc); acc = fmaf(a.y, w.y, acc);
            acc = fmaf(a.z, w.z, acc); acc = fmaf(a.w, w.w, acc);
        }
        __syncthreads();
    }
    float r = acc > 0.f ? acc : 0.f;
    cas[(long)(t0g + tl) * NC_ + c] = r;
    casS[tl][c] = r;
    __syncthreads();
    if (tid < 16) {
        float s = 0.f;
        #pragma unroll
        for (int c2 = 0; c2 < NC_; ++c2) s += casS[tid][c2];
        act[t0g + tid] = s;
    }
}

// ===================== fallback f32 conv (round-1, known-good) =====================
__global__ __launch_bounds__(256) void conv_embed_f32(
    const float* __restrict__ x,
    const float* __restrict__ w_rgb, const float* __restrict__ b_rgb,
    const float* __restrict__ w_flow, const float* __restrict__ b_flow,
    float* __restrict__ emb)
{
    __shared__ float Xs[2][16][132];
    __shared__ float Ws[2][16][3][68];
    const int tid = threadIdx.x;
    const int tx  = tid & 15;
    const int ty  = tid >> 4;
    const int co0 = blockIdx.x * 64;
    const int tb  = blockIdx.y;
    const int t0  = (tb % 6) * 128;
    const int b   = tb / 6;
    const float* xb = x + (long long)b * T_ * 2048;
    float acc[2][8][4];
    #pragma unroll
    for (int br = 0; br < 2; ++br)
        #pragma unroll
        for (int i = 0; i < 8; ++i)
            #pragma unroll
            for (int j = 0; j < 4; ++j) acc[br][i][j] = 0.f;
    for (int cc = 0; cc < 1024; cc += 16) {
        for (int it = tid; it < 1040; it += 256) {
            int br = (it >= 520);
            int r4 = it - br * 520;
            int r  = r4 >> 2;
            int cq = r4 & 3;
            int t  = t0 - 1 + r;
            float4 v = make_float4(0.f, 0.f, 0.f, 0.f);
            if (t >= 0 && t < T_)
                v = *reinterpret_cast<const float4*>(xb + (long long)t * 2048 + br * 1024 + cc + cq * 4);
            Xs[br][cq * 4 + 0][r] = v.x;
            Xs[br][cq * 4 + 1][r] = v.y;
            Xs[br][cq * 4 + 2][r] = v.z;
            Xs[br][cq * 4 + 3][r] = v.w;
        }
        for (int it = tid; it < 1536; it += 256) {
            int br = (it >= 768);
            int r  = it - br * 768;
            int co = r / 12;
            int fq = r - co * 12;
            const float* wsrc = (br ? w_flow : w_rgb) + ((long long)(co0 + co) * 1024 + cc) * 3 + fq * 4;
            float4 v = *reinterpret_cast<const float4*>(wsrc);
            float vv[4] = {v.x, v.y, v.z, v.w};
            #pragma unroll
            for (int j = 0; j < 4; ++j) {
                int f  = fq * 4 + j;
                int ci = f / 3;
                int kk = f - ci * 3;
                Ws[br][ci][kk][co] = vv[j];
            }
        }
        __syncthreads();
        #pragma unroll
        for (int ci = 0; ci < 16; ++ci) {
            float xr[2][12];
            #pragma unroll
            for (int br = 0; br < 2; ++br) {
                const float4* xp = reinterpret_cast<const float4*>(&Xs[br][ci][ty * 8]);
                float4 a0 = xp[0], a1 = xp[1], a2 = xp[2];
                xr[br][0] = a0.x; xr[br][1] = a0.y; xr[br][2]  = a0.z; xr[br][3]  = a0.w;
                xr[br][4] = a1.x; xr[br][5] = a1.y; xr[br][6]  = a1.z; xr[br][7]  = a1.w;
                xr[br][8] = a2.x; xr[br][9] = a2.y; xr[br][10] = a2.z; xr[br][11] = a2.w;
            }
            #pragma unroll
            for (int br = 0; br < 2; ++br) {
                #pragma unroll
                for (int k = 0; k < 3; ++k) {
                    const float4 bv = *reinterpret_cast<const float4*>(&Ws[br][ci][k][tx * 4]);
                    float bw[4] = {bv.x, bv.y, bv.z, bv.w};
                    #pragma unroll
                    for (int i = 0; i < 8; ++i)
                        #pragma unroll
                        for (int j = 0; j < 4; ++j)
                            acc[br][i][j] = fmaf(xr[br][i + k], bw[j], acc[br][i][j]);
                }
            }
        }
        __syncthreads();
    }
    const float4 brv = *reinterpret_cast<const float4*>(b_rgb + co0 + tx * 4);
    const float4 bfv = *reinterpret_cast<const float4*>(b_flow + co0 + tx * 4);
    float brr[4] = {brv.x, brv.y, brv.z, brv.w};
    float bff[4] = {bfv.x, bfv.y, bfv.z, bfv.w};
    #pragma unroll
    for (int i = 0; i < 8; ++i) {
        int t = t0 + ty * 8 + i;
        if (t < T_) {
            float ov[4];
            #pragma unroll
            for (int j = 0; j < 4; ++j) {
                float r = acc[0][i][j] + brr[j];
                float f = acc[1][i][j] + bff[j];
                r = r > 0.f ? r : 0.f;
                f = f > 0.f ? f : 0.f;
                ov[j] = r + f;
            }
            float4 o; o.x = ov[0]; o.y = ov[1]; o.z = ov[2]; o.w = ov[3];
            *reinterpret_cast<float4*>(emb + ((long long)b * T_ + t) * 2048 + co0 + tx * 4) = o;
        }
    }
}

// ===================== exact top-k machinery (512-thread sorts) =====================
__device__ inline float keyval64(unsigned long long k) {
    return __uint_as_float(~(unsigned)(k >> 32));
}

__device__ inline void bitonic512_u64(unsigned long long* keys, int tid)
{
    for (unsigned size = 2; size <= 1024; size <<= 1) {
        for (unsigned stride = size >> 1; stride > 0; stride >>= 1) {
            __syncthreads();
            unsigned i = ((tid & ~(stride - 1)) << 1) | (tid & (stride - 1));
            unsigned p = i + stride;
            bool asc = ((i & size) == 0);
            unsigned long long a = keys[i];
            unsigned long long c = keys[p];
            bool sw = asc ? (a > c) : (a < c);
            if (sw) { keys[i] = c; keys[p] = a; }
        }
    }
    __syncthreads();
}

__device__ inline void bitonic512_u32(unsigned* keys, int tid)
{
    for (unsigned size = 2; size <= 1024; size <<= 1) {
        for (unsigned stride = size >> 1; stride > 0; stride >>= 1) {
            __syncthreads();
            unsigned i = ((tid & ~(stride - 1)) << 1) | (tid & (stride - 1));
            unsigned p = i + stride;
            bool asc = ((i & size) == 0);
            unsigned a = keys[i];
            unsigned c = keys[p];
            bool sw = asc ? (a > c) : (a < c);
            if (sw) { keys[i] = c; keys[p] = a; }
        }
    }
    __syncthreads();
}

__device__ inline void bitonic_sort_u32_256(unsigned* keys, int tid)
{
    for (unsigned size = 2; size <= 1024; size <<= 1) {
        for (unsigned stride = size >> 1; stride > 0; stride >>= 1) {
            __syncthreads();
            for (int j = tid; j < 512; j += 256) {
                unsigned i = ((j & ~(stride - 1)) << 1) | (j & (stride - 1));
                unsigned p = i + stride;
                bool asc = ((i & size) == 0);
                unsigned a = keys[i];
                unsigned c = keys[p];
                bool sw = asc ? (a > c) : (a < c);
                if (sw) { keys[i] = c; keys[p] = a; }
            }
        }
    }
    __syncthreads();
}

// ===================== K3a: per-batch median + max (value-only u32 sort) ============
__global__ __launch_bounds__(512) void median_max(
    const float* __restrict__ act, float* __restrict__ medmax)
{
    const int b   = blockIdx.x;
    const int tid = threadIdx.x;
    __shared__ unsigned keys[1024];
    for (int p = tid; p < 1024; p += 512)
        keys[p] = (p < T_) ? ~__float_as_uint(act[b * T_ + p]) : 0xffffffffu;
    bitonic512_u32(keys, tid);
    if (tid == 0) {
        float v374 = __uint_as_float(~keys[374]);
        float v375 = __uint_as_float(~keys[375]);
        medmax[b * 2 + 0] = 0.5f * (v374 + v375);
        medmax[b * 2 + 1] = __uint_as_float(~keys[0]);
    }
}

// ===================== K3b: 64-way parallel top-k mining ============================
// block = (b, which): 0 act desc -> idx+EA, 1 (max-act) desc -> EB,
// 2 act*inner -> HA, 3 act*outer -> HB
__global__ __launch_bounds__(512) void topk4(
    const float* __restrict__ act, const float* __restrict__ medmax,
    float* __restrict__ idx_out, int* __restrict__ sel)
{
    const int b     = blockIdx.x >> 2;
    const int which = blockIdx.x & 3;
    const int tid   = threadIdx.x;
    __shared__ float av[T_];
    __shared__ unsigned char bin[T_];
    __shared__ unsigned long long keys[1024];

    for (int t = tid; t < T_; t += 512) av[t] = act[b * T_ + t];
    const float med = medmax[b * 2 + 0];
    const float mx  = medmax[b * 2 + 1];
    __syncthreads();
    if (which >= 2)
        for (int t = tid; t < T_; t += 512) bin[t] = (av[t] > med) ? 1 : 0;
    __syncthreads();

    for (int p = tid; p < 1024; p += 512) {
        unsigned long long k = ~0ull;
        if (p < T_) {
            float s;
            if (which == 0) s = av[p];
            else if (which == 1) s = mx - av[p];
            else if (which == 2) {
                int b0 = (p >= 1) ? bin[p - 1] : 0;
                int b1 = bin[p];
                int b2 = (p + 1 < T_) ? bin[p + 1] : 0;
                int e3 = b0 & b1 & b2;
                int e6 = 1;
                #pragma unroll
                for (int d = -3; d <= 2; ++d) {
                    int q = p + d;
                    e6 &= (q >= 0 && q < T_) ? (int)bin[q] : 0;
                }
                s = (e3 && !e6) ? av[p] : 0.f;
            } else {
                int b0 = (p >= 1) ? bin[p - 1] : 0;
                int b1 = bin[p];
                int b2 = (p + 1 < T_) ? bin[p + 1] : 0;
                int d3 = b0 | b1 | b2;
                int d6 = 0;
                #pragma unroll
                for (int d = -2; d <= 3; ++d) {
                    int q = p + d;
                    d6 |= (q >= 0 && q < T_) ? (int)bin[q] : 0;
                }
                s = (d6 && !d3) ? av[p] : 0.f;
            }
            k = ((unsigned long long)(~__float_as_uint(s)) << 32) | (unsigned)p;
        }
        keys[p] = k;
    }
    bitonic512_u64(keys, tid);

    const int kn = (which < 2) ? KNB_ : KB_;
    if (tid < kn) {
        int t = (int)(keys[tid] & 0xffffffffu);
        sel[(b * 4 + which) * 160 + tid] = t;
        if (which == 0) idx_out[b * KNB_ + tid] = (float)t;
    }
}

// ===================== K4: per-(b,c) top-150 mean =====================
__global__ __launch_bounds__(256) void video_topk(
    const float* __restrict__ cas, float* __restrict__ vs)
{
    const int bc  = blockIdx.x;
    const int b   = bc / NC_;
    const int c   = bc - b * NC_;
    const int tid = threadIdx.x;
    __shared__ unsigned keys[1024];
    __shared__ float red[4];
    for (int p = tid; p < 1024; p += 256)
        keys[p] = (p < T_) ? ~__float_as_uint(cas[((long long)b * T_ + p) * NC_ + c]) : 0xffffffffu;
    bitonic_sort_u32_256(keys, tid);
    float v = (tid < KNB_) ? __uint_as_float(~keys[tid]) : 0.f;
    #pragma unroll
    for (int off = 32; off > 0; off >>= 1) v += __shfl_down(v, off, 64);
    const int lane = tid & 63, wid = tid >> 6;
    if (lane == 0) red[wid] = v;
    __syncthreads();
    if (tid == 0) vs[bc] = (red[0] + red[1] + red[2] + red[3]) / 150.f;
}

__global__ void softmax20(const float* __restrict__ vs, float* __restrict__ out)
{
    const int b   = blockIdx.x;
    const int tid = threadIdx.x;
    float v = (tid < NC_) ? vs[b * NC_ + tid] : -INFINITY;
    float m = v;
    #pragma unroll
    for (int off = 32; off > 0; off >>= 1) m = fmaxf(m, __shfl_xor(m, off, 64));
    float e = (tid < NC_) ? expf(v - m) : 0.f;
    float s = e;
    #pragma unroll
    for (int off = 32; off > 0; off >>= 1) s += __shfl_xor(s, off, 64);
    if (tid < NC_) out[b * NC_ + tid] = e / s;
}

// ===================== K6: gather selected rows =====================
__global__ __launch_bounds__(256) void gather_rows(
    const float* __restrict__ emb, const int* __restrict__ sel, float* __restrict__ out)
{
    const int r = blockIdx.x;
    const int b = r / 374;
    const int q = r - b * 374;
    int g, p; long long dst;
    if (q < 150)      { g = 0; p = q;       dst = O_EA + (long long)(b * KNB_ + p) * 2048; }
    else if (q < 300) { g = 1; p = q - 150; dst = O_EB + (long long)(b * KNB_ + p) * 2048; }
    else if (q < 337) { g = 2; p = q - 300; dst = O_HA + (long long)(b * KB_ + p) * 2048; }
    else              { g = 3; p = q - 337; dst = O_HB + (long long)(b * KB_ + p) * 2048; }
    const int t = sel[(b * 4 + g) * 160 + p];
    const float4* src = reinterpret_cast<const float4*>(emb + ((long long)b * T_ + t) * 2048);
    float4* d = reinterpret_cast<float4*>(out + dst);
    for (int i = threadIdx.x; i < 512; i += 256) d[i] = src[i];
}

extern "C" void kernel_launch(void* const* d_in, const int* in_sizes, int n_in,
                              void* d_out, int out_size, void* d_ws, size_t ws_size,
                              hipStream_t stream)
{
    const float* x      = (const float*)d_in[0];
    const float* w_rgb  = (const float*)d_in[1];
    const float* b_rgb  = (const float*)d_in[2];
    const float* w_flow = (const float*)d_in[3];
    const float* b_flow = (const float*)d_in[4];
    const float* w_cls  = (const float*)d_in[5];

    float* out  = (float*)d_out;
    float* emb  = out + O_EMB;
    float* cas  = out + O_CAS;
    float* act  = out + O_ACT;
    float* idxo = out + O_IDX;

    const bool fast = (ws_size >= (size_t)W_NEED);

    int*   sel;
    float* vs;
    float* medmax;
    if (fast) {
        sel    = (int*)((char*)d_ws + W_SEL);
        vs     = (float*)((char*)d_ws + W_VS);
        medmax = (float*)((char*)d_ws + W_MED);
        _Float16* xh = (_Float16*)((char*)d_ws + W_XHI);
        _Float16* xl = (_Float16*)((char*)d_ws + W_XLO);
        _Float16* wh = (_Float16*)((char*)d_ws + W_WHI);
        _Float16* wl = (_Float16*)((char*)d_ws + W_WLO);

        xsplit<<<24064, 256, 0, stream>>>(x, xh, xl);
        wsplit<<<4096, 64, 0, stream>>>(w_rgb, w_flow, wh, wl);
        conv_mfma<0><<<dim3(16, 64), 256, 0, stream>>>(xh, xl, wh, wl, b_rgb, emb);
        conv_mfma<1><<<dim3(16, 64), 256, 0, stream>>>(xh, xl, wh, wl, b_flow, emb);
    } else {
        sel    = (int*)d_ws;
        vs     = (float*)((char*)d_ws + 40960);
        medmax = (float*)((char*)d_ws + 40960 + 4096);
        conv_embed_f32<<<dim3(32, 96), 256, 0, stream>>>(x, w_rgb, b_rgb, w_flow, b_flow, emb);
    }

    cas_tc<<<750, 320, 0, stream>>>(emb, w_cls, cas, act);
    median_max<<<B_, 512, 0, stream>>>(act, medmax);
    topk4<<<B_ * 4, 512, 0, stream>>>(act, medmax, idxo, sel);
    video_topk<<<B_ * NC_, 256, 0, stream>>>(cas, vs);
    softmax20<<<B_, 64, 0, stream>>>(vs, out + O_VS);
    gather_rows<<<B_ * 374, 256, 0, stream>>>(emb, sel, out);
}

// Round 5
// 1110.649 us; speedup vs baseline: 1.1292x; 1.0234x over previous
//
#include <hip/hip_runtime.h>
#include <stdint.h>
#include <math.h>

#define B_   16
#define T_   750
#define NC_  20
#define KNB_ 150   // T/5
#define KB_  37    // T/20

typedef _Float16 f16x8 __attribute__((ext_vector_type(8)));
typedef _Float16 f16x4 __attribute__((ext_vector_type(4)));
typedef float    f32x4 __attribute__((ext_vector_type(4)));

// ---- flat output layout (f32), concatenated in reference return order ----
static constexpr long long O_VS  = 0;                       // [16,20]
static constexpr long long O_EA  = 320;                     // [16,150,2048]
static constexpr long long O_EB  = 320 + 4915200LL;
static constexpr long long O_HA  = 320 + 2*4915200LL;
static constexpr long long O_HB  = O_HA + 1212416LL;
static constexpr long long O_IDX = O_HB + 1212416LL;        // [16,150]
static constexpr long long O_ACT = O_IDX + 2400LL;          // [16,750]
static constexpr long long O_CAS = O_ACT + 12000LL;         // [16,750,20]
static constexpr long long O_EMB = O_CAS + 240000LL;        // [16,750,2048]

// ---- workspace layout (fast path), bytes ----
static constexpr long long WX_ELE   = 16LL * 752 * 2048;          // f16 elements
static constexpr long long W_XHI    = 0;
static constexpr long long W_XLO    = W_XHI + WX_ELE * 2;
static constexpr long long WW_ELE   = 2LL * 16 * 32 * 12288;
static constexpr long long W_WHI    = W_XLO + WX_ELE * 2;
static constexpr long long W_WLO    = W_WHI + WW_ELE * 2;
static constexpr long long W_SEL    = W_WLO + WW_ELE * 2;         // 16*4*160 ints
static constexpr long long W_VS     = W_SEL + 40960;
static constexpr long long W_MED    = W_VS + 4096;                // 16*2 floats
static constexpr long long W_NEED   = W_MED + 256;

__device__ __forceinline__ void gload16(const void* g, void* l) {
    __builtin_amdgcn_global_load_lds(
        (const __attribute__((address_space(1))) unsigned int*)g,
        (__attribute__((address_space(3))) unsigned int*)l, 16, 0, 0);
}

// =====================================================================
// P1: split x -> x_hi/x_lo f16, padded rows (t=-1 and t=750) zeroed
// =====================================================================
__global__ __launch_bounds__(256) void xsplit(
    const float* __restrict__ x, _Float16* __restrict__ xh, _Float16* __restrict__ xl)
{
    long i = (long)blockIdx.x * 256 + threadIdx.x;
    int row = (int)(i >> 9);
    int c4  = (int)(i & 511);
    int b = row / 752, tr = row - b * 752;
    int t = tr - 1;
    float4 v = make_float4(0.f, 0.f, 0.f, 0.f);
    if (t >= 0 && t < T_)
        v = *reinterpret_cast<const float4*>(x + ((long)(b * T_ + t) * 2048 + c4 * 4));
    float vv[4] = {v.x, v.y, v.z, v.w};
    f16x4 h, l;
    #pragma unroll
    for (int j = 0; j < 4; ++j) {
        _Float16 hi = (_Float16)vv[j];
        h[j] = hi;
        l[j] = (_Float16)(vv[j] - (float)hi);
    }
    long o = (long)row * 2048 + c4 * 4;
    *reinterpret_cast<f16x4*>(xh + o) = h;
    *reinterpret_cast<f16x4*>(xl + o) = l;
}

// =====================================================================
// P2: split w*512 -> frag-contiguous image [br][nt][chunk][k][co128][g4][8]
// =====================================================================
__global__ __launch_bounds__(64) void wsplit(
    const float* __restrict__ w_rgb, const float* __restrict__ w_flow,
    _Float16* __restrict__ wh, _Float16* __restrict__ wl)
{
    const int br   = blockIdx.x >> 11;
    const int co_g = blockIdx.x & 2047;
    const int tid  = threadIdx.x;
    const float* w = (br ? w_flow : w_rgb) + (long)co_g * 3072;   // [ci][k]
    __shared__ float wsrc[3072];
    for (int i = tid; i < 768; i += 64)
        reinterpret_cast<float4*>(wsrc)[i] = reinterpret_cast<const float4*>(w)[i];
    __syncthreads();
    const int nt = co_g >> 7, co = co_g & 127;
    for (int p = tid; p < 384; p += 64) {           // 128 octets x 3 taps
        int oct = p / 3, k = p - oct * 3;
        int chunk = oct >> 2, g = oct & 3;
        f16x8 h, l;
        #pragma unroll
        for (int j = 0; j < 8; ++j) {
            float v = wsrc[(oct * 8 + j) * 3 + k] * 512.f;
            _Float16 hi = (_Float16)v;
            h[j] = hi;
            l[j] = (_Float16)(v - (float)hi);
        }
        long o = ((long)(br * 16 + nt) * 32 + chunk) * 12288 + k * 4096 + co * 32 + g * 8;
        *reinterpret_cast<f16x8*>(wh + o) = h;
        *reinterpret_cast<f16x8*>(wl + o) = l;
    }
}

// =====================================================================
// K1: conv1d(K=3,pad=1), split-f16 MFMA 16x16x32. Tile 192t x 128co,
// 4 waves (each 96t x 64co = 6x4 frags). X double-buffered in LDS:
// stage chunk c+1 while computing chunk c; ONE barrier per chunk at end
// (its vmcnt(0) drain waits on loads issued ~8k cycles earlier).
// W loaded global->reg (frag-contiguous, L2-resident), tap-pipelined.
// ADD=0: rgb (store), ADD=1: flow (+=).
// =====================================================================
template<int ADD>
__global__ __launch_bounds__(256, 2) void conv_mfma(
    const _Float16* __restrict__ xh, const _Float16* __restrict__ xl,
    const _Float16* __restrict__ wh, const _Float16* __restrict__ wl,
    const float* __restrict__ bias, float* __restrict__ emb)
{
    __shared__ _Float16 XhL[2 * 6272], XlL[2 * 6272];   // dbuf: 196 rows x 32 f16 (swizzled)

    const int tid  = threadIdx.x;
    const int lane = tid & 63;
    const int wid  = tid >> 6;
    const int wm = wid >> 1, wn = wid & 1;
    const int lrow = lane & 15, lg = lane >> 4;
    const int nt = blockIdx.x;                 // natural order: 16 nt share X tile
    const int b  = blockIdx.y >> 2;
    const int tt = blockIdx.y & 3;
    const int t0 = tt * 192;

    f32x4 acc[6][4];
    #pragma unroll
    for (int m = 0; m < 6; ++m)
        #pragma unroll
        for (int n = 0; n < 4; ++n)
            acc[m][n] = (f32x4){0.f, 0.f, 0.f, 0.f};

    const long xrowbase = (long)b * 752 + t0;
    const int  cibase0  = ADD * 1024;
    const long wslice   = ((long)(ADD * 16 + nt) * 32) * 12288;
    const int  wlane    = (wn * 64 + lrow) * 32 + lg * 8;

    // ---- stage chunk 0 into buffer 0 ----
    {
        const int cibase = cibase0;
        for (int s = tid; s < 776; s += 256) {
            int r = s >> 2, q = s & 3;
            int g = q ^ ((r >> 1) & 3);
            long goff = (xrowbase + r) * 2048 + cibase + g * 8;
            int lbase = (s & ~63) * 8;
            gload16(xh + goff, XhL + lbase);
            gload16(xl + goff, XlL + lbase);
        }
    }
    __syncthreads();

    for (int chunk = 0; chunk < 32; ++chunk) {
        const int cur = chunk & 1;
        const long wb = wslice + (long)chunk * 12288 + wlane;
        f16x8 bh0[4], bl0[4], bh1[4], bl1[4];
        // W frags for k=0 (VGPR loads; waits auto-inserted before first use)
        #pragma unroll
        for (int n = 0; n < 4; ++n) {
            bh0[n] = *reinterpret_cast<const f16x8*>(wh + wb + n * 512);
            bl0[n] = *reinterpret_cast<const f16x8*>(wl + wb + n * 512);
        }
        // ---- issue stage of chunk+1 into the other buffer (no wait) ----
        if (chunk < 31) {
            const int cibase = cibase0 + (chunk + 1) * 32;
            const int dstb   = (cur ^ 1) * 6272;
            for (int s = tid; s < 776; s += 256) {
                int r = s >> 2, q = s & 3;
                int g = q ^ ((r >> 1) & 3);
                long goff = (xrowbase + r) * 2048 + cibase + g * 8;
                int lbase = dstb + (s & ~63) * 8;
                gload16(xh + goff, XhL + lbase);
                gload16(xl + goff, XlL + lbase);
            }
        }
        const int xb0 = cur * 6272;

        // ================= k = 0 (prefetch k=1 W frags) =================
        #pragma unroll
        for (int n = 0; n < 4; ++n) {
            bh1[n] = *reinterpret_cast<const f16x8*>(wh + wb + 4096 + n * 512);
            bl1[n] = *reinterpret_cast<const f16x8*>(wl + wb + 4096 + n * 512);
        }
        #pragma unroll
        for (int m = 0; m < 6; ++m) {
            int r = wm * 96 + m * 16 + lrow;
            int off = xb0 + r * 32 + ((lg ^ ((r >> 1) & 3)) * 8);
            f16x8 ah = *reinterpret_cast<const f16x8*>(&XhL[off]);
            f16x8 al = *reinterpret_cast<const f16x8*>(&XlL[off]);
            #pragma unroll
            for (int n = 0; n < 4; ++n) {
                acc[m][n] = __builtin_amdgcn_mfma_f32_16x16x32_f16(ah, bh0[n], acc[m][n], 0, 0, 0);
                acc[m][n] = __builtin_amdgcn_mfma_f32_16x16x32_f16(al, bh0[n], acc[m][n], 0, 0, 0);
                acc[m][n] = __builtin_amdgcn_mfma_f32_16x16x32_f16(ah, bl0[n], acc[m][n], 0, 0, 0);
            }
        }
        // ================= k = 1 (prefetch k=2 into buf0) ===============
        #pragma unroll
        for (int n = 0; n < 4; ++n) {
            bh0[n] = *reinterpret_cast<const f16x8*>(wh + wb + 8192 + n * 512);
            bl0[n] = *reinterpret_cast<const f16x8*>(wl + wb + 8192 + n * 512);
        }
        #pragma unroll
        for (int m = 0; m < 6; ++m) {
            int r = wm * 96 + m * 16 + lrow + 1;
            int off = xb0 + r * 32 + ((lg ^ ((r >> 1) & 3)) * 8);
            f16x8 ah = *reinterpret_cast<const f16x8*>(&XhL[off]);
            f16x8 al = *reinterpret_cast<const f16x8*>(&XlL[off]);
            #pragma unroll
            for (int n = 0; n < 4; ++n) {
                acc[m][n] = __builtin_amdgcn_mfma_f32_16x16x32_f16(ah, bh1[n], acc[m][n], 0, 0, 0);
                acc[m][n] = __builtin_amdgcn_mfma_f32_16x16x32_f16(al, bh1[n], acc[m][n], 0, 0, 0);
                acc[m][n] = __builtin_amdgcn_mfma_f32_16x16x32_f16(ah, bl1[n], acc[m][n], 0, 0, 0);
            }
        }
        // ================= k = 2 ========================================
        #pragma unroll
        for (int m = 0; m < 6; ++m) {
            int r = wm * 96 + m * 16 + lrow + 2;
            int off = xb0 + r * 32 + ((lg ^ ((r >> 1) & 3)) * 8);
            f16x8 ah = *reinterpret_cast<const f16x8*>(&XhL[off]);
            f16x8 al = *reinterpret_cast<const f16x8*>(&XlL[off]);
            #pragma unroll
            for (int n = 0; n < 4; ++n) {
                acc[m][n] = __builtin_amdgcn_mfma_f32_16x16x32_f16(ah, bh0[n], acc[m][n], 0, 0, 0);
                acc[m][n] = __builtin_amdgcn_mfma_f32_16x16x32_f16(al, bh0[n], acc[m][n], 0, 0, 0);
                acc[m][n] = __builtin_amdgcn_mfma_f32_16x16x32_f16(ah, bl0[n], acc[m][n], 0, 0, 0);
            }
        }
        // one barrier per chunk: drains prefetch (landed under compute) and
        // guards the buffer being read from next iteration's stage writes.
        __syncthreads();
    }

    // ---- epilogue: relu(acc/512 + bias); ADD pass accumulates ----
    const float sc = 1.f / 512.f;
    #pragma unroll
    for (int n = 0; n < 4; ++n) {
        const int co = nt * 128 + wn * 64 + n * 16 + lrow;
        const float bs = bias[co];
        #pragma unroll
        for (int m = 0; m < 6; ++m) {
            #pragma unroll
            for (int rg = 0; rg < 4; ++rg) {
                int t = t0 + wm * 96 + m * 16 + lg * 4 + rg;
                if (t < T_) {
                    long o = ((long)b * T_ + t) * 2048 + co;
                    float v = fmaxf(fmaf(acc[m][n][rg], sc, bs), 0.f);
                    if (ADD) emb[o] += v;
                    else     emb[o]  = v;
                }
            }
        }
    }
}

// =====================================================================
// K2: cas + actionness. Thread-per-(t,c): no cross-lane reduction.
// =====================================================================
__global__ __launch_bounds__(320) void cas_tc(
    const float* __restrict__ emb, const float* __restrict__ wcls,
    float* __restrict__ cas, float* __restrict__ act)
{
    const int t0g = blockIdx.x * 16;          // flat row base (b*T + t)
    const int tid = threadIdx.x;
    const int tl  = tid / 20, c = tid % 20;   // 16 x 20 = 320
    __shared__ float embS[16][132];
    __shared__ float wS[20][132];
    __shared__ float casS[16][20];

    float acc = 0.f;
    for (int cc = 0; cc < 2048; cc += 128) {
        for (int s = tid; s < 512; s += 320) {
            int r = s >> 5, q = s & 31;
            *reinterpret_cast<float4*>(&embS[r][q * 4]) =
                *reinterpret_cast<const float4*>(&emb[((long)t0g + r) * 2048 + cc + q * 4]);
        }
        for (int s = tid; s < 640; s += 320) {
            int r = s >> 5, q = s & 31;
            *reinterpret_cast<float4*>(&wS[r][q * 4]) =
                *reinterpret_cast<const float4*>(&wcls[(long)r * 2048 + cc + q * 4]);
        }
        __syncthreads();
        #pragma unroll
        for (int q = 0; q < 32; ++q) {
            float4 a = *reinterpret_cast<const float4*>(&embS[tl][q * 4]);
            float4 w = *reinterpret_cast<const float4*>(&wS[c][q * 4]);
            acc = fmaf(a.x, w.x, acc); acc = fmaf(a.y, w.y, acc);
            acc = fmaf(a.z, w.z, acc); acc = fmaf(a.w, w.w, acc);
        }
        __syncthreads();
    }
    float r = acc > 0.f ? acc : 0.f;
    cas[(long)(t0g + tl) * NC_ + c] = r;
    casS[tl][c] = r;
    __syncthreads();
    if (tid < 16) {
        float s = 0.f;
        #pragma unroll
        for (int c2 = 0; c2 < NC_; ++c2) s += casS[tid][c2];
        act[t0g + tid] = s;
    }
}

// ===================== fallback f32 conv (round-1, known-good) =====================
__global__ __launch_bounds__(256) void conv_embed_f32(
    const float* __restrict__ x,
    const float* __restrict__ w_rgb, const float* __restrict__ b_rgb,
    const float* __restrict__ w_flow, const float* __restrict__ b_flow,
    float* __restrict__ emb)
{
    __shared__ float Xs[2][16][132];
    __shared__ float Ws[2][16][3][68];
    const int tid = threadIdx.x;
    const int tx  = tid & 15;
    const int ty  = tid >> 4;
    const int co0 = blockIdx.x * 64;
    const int tb  = blockIdx.y;
    const int t0  = (tb % 6) * 128;
    const int b   = tb / 6;
    const float* xb = x + (long long)b * T_ * 2048;
    float acc[2][8][4];
    #pragma unroll
    for (int br = 0; br < 2; ++br)
        #pragma unroll
        for (int i = 0; i < 8; ++i)
            #pragma unroll
            for (int j = 0; j < 4; ++j) acc[br][i][j] = 0.f;
    for (int cc = 0; cc < 1024; cc += 16) {
        for (int it = tid; it < 1040; it += 256) {
            int br = (it >= 520);
            int r4 = it - br * 520;
            int r  = r4 >> 2;
            int cq = r4 & 3;
            int t  = t0 - 1 + r;
            float4 v = make_float4(0.f, 0.f, 0.f, 0.f);
            if (t >= 0 && t < T_)
                v = *reinterpret_cast<const float4*>(xb + (long long)t * 2048 + br * 1024 + cc + cq * 4);
            Xs[br][cq * 4 + 0][r] = v.x;
            Xs[br][cq * 4 + 1][r] = v.y;
            Xs[br][cq * 4 + 2][r] = v.z;
            Xs[br][cq * 4 + 3][r] = v.w;
        }
        for (int it = tid; it < 1536; it += 256) {
            int br = (it >= 768);
            int r  = it - br * 768;
            int co = r / 12;
            int fq = r - co * 12;
            const float* wsrc = (br ? w_flow : w_rgb) + ((long long)(co0 + co) * 1024 + cc) * 3 + fq * 4;
            float4 v = *reinterpret_cast<const float4*>(wsrc);
            float vv[4] = {v.x, v.y, v.z, v.w};
            #pragma unroll
            for (int j = 0; j < 4; ++j) {
                int f  = fq * 4 + j;
                int ci = f / 3;
                int kk = f - ci * 3;
                Ws[br][ci][kk][co] = vv[j];
            }
        }
        __syncthreads();
        #pragma unroll
        for (int ci = 0; ci < 16; ++ci) {
            float xr[2][12];
            #pragma unroll
            for (int br = 0; br < 2; ++br) {
                const float4* xp = reinterpret_cast<const float4*>(&Xs[br][ci][ty * 8]);
                float4 a0 = xp[0], a1 = xp[1], a2 = xp[2];
                xr[br][0] = a0.x; xr[br][1] = a0.y; xr[br][2]  = a0.z; xr[br][3]  = a0.w;
                xr[br][4] = a1.x; xr[br][5] = a1.y; xr[br][6]  = a1.z; xr[br][7]  = a1.w;
                xr[br][8] = a2.x; xr[br][9] = a2.y; xr[br][10] = a2.z; xr[br][11] = a2.w;
            }
            #pragma unroll
            for (int br = 0; br < 2; ++br) {
                #pragma unroll
                for (int k = 0; k < 3; ++k) {
                    const float4 bv = *reinterpret_cast<const float4*>(&Ws[br][ci][k][tx * 4]);
                    float bw[4] = {bv.x, bv.y, bv.z, bv.w};
                    #pragma unroll
                    for (int i = 0; i < 8; ++i)
                        #pragma unroll
                        for (int j = 0; j < 4; ++j)
                            acc[br][i][j] = fmaf(xr[br][i + k], bw[j], acc[br][i][j]);
                }
            }
        }
        __syncthreads();
    }
    const float4 brv = *reinterpret_cast<const float4*>(b_rgb + co0 + tx * 4);
    const float4 bfv = *reinterpret_cast<const float4*>(b_flow + co0 + tx * 4);
    float brr[4] = {brv.x, brv.y, brv.z, brv.w};
    float bff[4] = {bfv.x, bfv.y, bfv.z, bfv.w};
    #pragma unroll
    for (int i = 0; i < 8; ++i) {
        int t = t0 + ty * 8 + i;
        if (t < T_) {
            float ov[4];
            #pragma unroll
            for (int j = 0; j < 4; ++j) {
                float r = acc[0][i][j] + brr[j];
                float f = acc[1][i][j] + bff[j];
                r = r > 0.f ? r : 0.f;
                f = f > 0.f ? f : 0.f;
                ov[j] = r + f;
            }
            float4 o; o.x = ov[0]; o.y = ov[1]; o.z = ov[2]; o.w = ov[3];
            *reinterpret_cast<float4*>(emb + ((long long)b * T_ + t) * 2048 + co0 + tx * 4) = o;
        }
    }
}

// ===================== exact top-k machinery (512-thread sorts) =====================
__device__ inline void bitonic512_u64(unsigned long long* keys, int tid)
{
    for (unsigned size = 2; size <= 1024; size <<= 1) {
        for (unsigned stride = size >> 1; stride > 0; stride >>= 1) {
            __syncthreads();
            unsigned i = ((tid & ~(stride - 1)) << 1) | (tid & (stride - 1));
            unsigned p = i + stride;
            bool asc = ((i & size) == 0);
            unsigned long long a = keys[i];
            unsigned long long c = keys[p];
            bool sw = asc ? (a > c) : (a < c);
            if (sw) { keys[i] = c; keys[p] = a; }
        }
    }
    __syncthreads();
}

__device__ inline void bitonic512_u32(unsigned* keys, int tid)
{
    for (unsigned size = 2; size <= 1024; size <<= 1) {
        for (unsigned stride = size >> 1; stride > 0; stride >>= 1) {
            __syncthreads();
            unsigned i = ((tid & ~(stride - 1)) << 1) | (tid & (stride - 1));
            unsigned p = i + stride;
            bool asc = ((i & size) == 0);
            unsigned a = keys[i];
            unsigned c = keys[p];
            bool sw = asc ? (a > c) : (a < c);
            if (sw) { keys[i] = c; keys[p] = a; }
        }
    }
    __syncthreads();
}

__device__ inline void bitonic_sort_u32_256(unsigned* keys, int tid)
{
    for (unsigned size = 2; size <= 1024; size <<= 1) {
        for (unsigned stride = size >> 1; stride > 0; stride >>= 1) {
            __syncthreads();
            for (int j = tid; j < 512; j += 256) {
                unsigned i = ((j & ~(stride - 1)) << 1) | (j & (stride - 1));
                unsigned p = i + stride;
                bool asc = ((i & size) == 0);
                unsigned a = keys[i];
                unsigned c = keys[p];
                bool sw = asc ? (a > c) : (a < c);
                if (sw) { keys[i] = c; keys[p] = a; }
            }
        }
    }
    __syncthreads();
}

// ===================== K3a: per-batch median + max =====================
__global__ __launch_bounds__(512) void median_max(
    const float* __restrict__ act, float* __restrict__ medmax)
{
    const int b   = blockIdx.x;
    const int tid = threadIdx.x;
    __shared__ unsigned keys[1024];
    for (int p = tid; p < 1024; p += 512)
        keys[p] = (p < T_) ? ~__float_as_uint(act[b * T_ + p]) : 0xffffffffu;
    bitonic512_u32(keys, tid);
    if (tid == 0) {
        float v374 = __uint_as_float(~keys[374]);
        float v375 = __uint_as_float(~keys[375]);
        medmax[b * 2 + 0] = 0.5f * (v374 + v375);
        medmax[b * 2 + 1] = __uint_as_float(~keys[0]);
    }
}

// ===================== K3b: 64-way parallel top-k mining ====================
__global__ __launch_bounds__(512) void topk4(
    const float* __restrict__ act, const float* __restrict__ medmax,
    float* __restrict__ idx_out, int* __restrict__ sel)
{
    const int b     = blockIdx.x >> 2;
    const int which = blockIdx.x & 3;
    const int tid   = threadIdx.x;
    __shared__ float av[T_];
    __shared__ unsigned char bin[T_];
    __shared__ unsigned long long keys[1024];

    for (int t = tid; t < T_; t += 512) av[t] = act[b * T_ + t];
    const float med = medmax[b * 2 + 0];
    const float mx  = medmax[b * 2 + 1];
    __syncthreads();
    if (which >= 2)
        for (int t = tid; t < T_; t += 512) bin[t] = (av[t] > med) ? 1 : 0;
    __syncthreads();

    for (int p = tid; p < 1024; p += 512) {
        unsigned long long k = ~0ull;
        if (p < T_) {
            float s;
            if (which == 0) s = av[p];
            else if (which == 1) s = mx - av[p];
            else if (which == 2) {
                int b0 = (p >= 1) ? bin[p - 1] : 0;
                int b1 = bin[p];
                int b2 = (p + 1 < T_) ? bin[p + 1] : 0;
                int e3 = b0 & b1 & b2;
                int e6 = 1;
                #pragma unroll
                for (int d = -3; d <= 2; ++d) {
                    int q = p + d;
                    e6 &= (q >= 0 && q < T_) ? (int)bin[q] : 0;
                }
                s = (e3 && !e6) ? av[p] : 0.f;
            } else {
                int b0 = (p >= 1) ? bin[p - 1] : 0;
                int b1 = bin[p];
                int b2 = (p + 1 < T_) ? bin[p + 1] : 0;
                int d3 = b0 | b1 | b2;
                int d6 = 0;
                #pragma unroll
                for (int d = -2; d <= 3; ++d) {
                    int q = p + d;
                    d6 |= (q >= 0 && q < T_) ? (int)bin[q] : 0;
                }
                s = (d6 && !d3) ? av[p] : 0.f;
            }
            k = ((unsigned long long)(~__float_as_uint(s)) << 32) | (unsigned)p;
        }
        keys[p] = k;
    }
    bitonic512_u64(keys, tid);

    const int kn = (which < 2) ? KNB_ : KB_;
    if (tid < kn) {
        int t = (int)(keys[tid] & 0xffffffffu);
        sel[(b * 4 + which) * 160 + tid] = t;
        if (which == 0) idx_out[b * KNB_ + tid] = (float)t;
    }
}

// ===================== K4: per-(b,c) top-150 mean =====================
__global__ __launch_bounds__(256) void video_topk(
    const float* __restrict__ cas, float* __restrict__ vs)
{
    const int bc  = blockIdx.x;
    const int b   = bc / NC_;
    const int c   = bc - b * NC_;
    const int tid = threadIdx.x;
    __shared__ unsigned keys[1024];
    __shared__ float red[4];
    for (int p = tid; p < 1024; p += 256)
        keys[p] = (p < T_) ? ~__float_as_uint(cas[((long long)b * T_ + p) * NC_ + c]) : 0xffffffffu;
    bitonic_sort_u32_256(keys, tid);
    float v = (tid < KNB_) ? __uint_as_float(~keys[tid]) : 0.f;
    #pragma unroll
    for (int off = 32; off > 0; off >>= 1) v += __shfl_down(v, off, 64);
    const int lane = tid & 63, wid = tid >> 6;
    if (lane == 0) red[wid] = v;
    __syncthreads();
    if (tid == 0) vs[bc] = (red[0] + red[1] + red[2] + red[3]) / 150.f;
}

__global__ void softmax20(const float* __restrict__ vs, float* __restrict__ out)
{
    const int b   = blockIdx.x;
    const int tid = threadIdx.x;
    float v = (tid < NC_) ? vs[b * NC_ + tid] : -INFINITY;
    float m = v;
    #pragma unroll
    for (int off = 32; off > 0; off >>= 1) m = fmaxf(m, __shfl_xor(m, off, 64));
    float e = (tid < NC_) ? expf(v - m) : 0.f;
    float s = e;
    #pragma unroll
    for (int off = 32; off > 0; off >>= 1) s += __shfl_xor(s, off, 64);
    if (tid < NC_) out[b * NC_ + tid] = e / s;
}

// ===================== K6: gather selected rows =====================
__global__ __launch_bounds__(256) void gather_rows(
    const float* __restrict__ emb, const int* __restrict__ sel, float* __restrict__ out)
{
    const int r = blockIdx.x;
    const int b = r / 374;
    const int q = r - b * 374;
    int g, p; long long dst;
    if (q < 150)      { g = 0; p = q;       dst = O_EA + (long long)(b * KNB_ + p) * 2048; }
    else if (q < 300) { g = 1; p = q - 150; dst = O_EB + (long long)(b * KNB_ + p) * 2048; }
    else if (q < 337) { g = 2; p = q - 300; dst = O_HA + (long long)(b * KB_ + p) * 2048; }
    else              { g = 3; p = q - 337; dst = O_HB + (long long)(b * KB_ + p) * 2048; }
    const int t = sel[(b * 4 + g) * 160 + p];
    const float4* src = reinterpret_cast<const float4*>(emb + ((long long)b * T_ + t) * 2048);
    float4* d = reinterpret_cast<float4*>(out + dst);
    for (int i = threadIdx.x; i < 512; i += 256) d[i] = src[i];
}

extern "C" void kernel_launch(void* const* d_in, const int* in_sizes, int n_in,
                              void* d_out, int out_size, void* d_ws, size_t ws_size,
                              hipStream_t stream)
{
    const float* x      = (const float*)d_in[0];
    const float* w_rgb  = (const float*)d_in[1];
    const float* b_rgb  = (const float*)d_in[2];
    const float* w_flow = (const float*)d_in[3];
    const float* b_flow = (const float*)d_in[4];
    const float* w_cls  = (const float*)d_in[5];

    float* out  = (float*)d_out;
    float* emb  = out + O_EMB;
    float* cas  = out + O_CAS;
    float* act  = out + O_ACT;
    float* idxo = out + O_IDX;

    const bool fast = (ws_size >= (size_t)W_NEED);

    int*   sel;
    float* vs;
    float* medmax;
    if (fast) {
        sel    = (int*)((char*)d_ws + W_SEL);
        vs     = (float*)((char*)d_ws + W_VS);
        medmax = (float*)((char*)d_ws + W_MED);
        _Float16* xh = (_Float16*)((char*)d_ws + W_XHI);
        _Float16* xl = (_Float16*)((char*)d_ws + W_XLO);
        _Float16* wh = (_Float16*)((char*)d_ws + W_WHI);
        _Float16* wl = (_Float16*)((char*)d_ws + W_WLO);

        xsplit<<<24064, 256, 0, stream>>>(x, xh, xl);
        wsplit<<<4096, 64, 0, stream>>>(w_rgb, w_flow, wh, wl);
        conv_mfma<0><<<dim3(16, 64), 256, 0, stream>>>(xh, xl, wh, wl, b_rgb, emb);
        conv_mfma<1><<<dim3(16, 64), 256, 0, stream>>>(xh, xl, wh, wl, b_flow, emb);
    } else {
        sel    = (int*)d_ws;
        vs     = (float*)((char*)d_ws + 40960);
        medmax = (float*)((char*)d_ws + 40960 + 4096);
        conv_embed_f32<<<dim3(32, 96), 256, 0, stream>>>(x, w_rgb, b_rgb, w_flow, b_flow, emb);
    }

    cas_tc<<<750, 320, 0, stream>>>(emb, w_cls, cas, act);
    median_max<<<B_, 512, 0, stream>>>(act, medmax);
    topk4<<<B_ * 4, 512, 0, stream>>>(act, medmax, idxo, sel);
    video_topk<<<B_ * NC_, 256, 0, stream>>>(cas, vs);
    softmax20<<<B_, 64, 0, stream>>>(vs, out + O_VS);
    gather_rows<<<B_ * 374, 256, 0, stream>>>(emb, sel, out);
}